// Round 1
// baseline (23.625 us; speedup 1.0000x reference)
//
#include <hip/hip_runtime.h>

#define PAGE 16

// Kernel 1: block-wide exclusive scans over the batch (B <= 1024).
// Produces out_start[b] (exclusive cumsum of extend) and
// page_start[b] (exclusive cumsum of new_pages) into workspace.
__global__ void scan_kernel(const int* __restrict__ pre_lens,
                            const int* __restrict__ seq_lens,
                            int* __restrict__ out_start,
                            int* __restrict__ page_start,
                            int B) {
    __shared__ int s1[1024];
    __shared__ int s2[1024];
    int tid = threadIdx.x;
    int pre = 0, seq = 0;
    if (tid < B) { pre = pre_lens[tid]; seq = seq_lens[tid]; }
    int ext = seq - pre;
    int npb = (pre + PAGE - 1) / PAGE;
    int npa = (seq + PAGE - 1) / PAGE;
    int npg = npa - npb;
    s1[tid] = ext;
    s2[tid] = npg;
    __syncthreads();
    // Hillis-Steele inclusive scan over 1024 elements
    for (int off = 1; off < 1024; off <<= 1) {
        int v1 = (tid >= off) ? s1[tid - off] : 0;
        int v2 = (tid >= off) ? s2[tid - off] : 0;
        __syncthreads();
        s1[tid] += v1;
        s2[tid] += v2;
        __syncthreads();
    }
    if (tid < B) {
        out_start[tid]  = s1[tid] - ext;  // exclusive
        page_start[tid] = s2[tid] - npg;  // exclusive
    }
}

// Kernel 2: one block per batch element; write its extend-token segment.
__global__ void fill_kernel(const int* __restrict__ pre_lens,
                            const int* __restrict__ seq_lens,
                            const int* __restrict__ last_loc,
                            const int* __restrict__ free_page,
                            const int* __restrict__ out_start,
                            const int* __restrict__ page_start,
                            int* __restrict__ out,
                            int n_free) {
    int b = blockIdx.x;
    int pre  = pre_lens[b];
    int seq  = seq_lens[b];
    int ext  = seq - pre;
    int last = last_loc[b];
    int os   = out_start[b];
    int ps   = page_start[b];
    int npb  = (pre + PAGE - 1) / PAGE;
    int boundary = npb * PAGE;          // end of partial first page
    int base = ps - npb;                // pidx = base + pos/16

    for (int t = threadIdx.x; t < ext; t += blockDim.x) {
        int pos = pre + t;
        int val;
        if (pos < boundary) {
            val = last + 1 + t;
        } else {
            int pidx = base + (pos >> 4);
            // defensive clamp (matches reference clip; in-range by construction)
            pidx = min(max(pidx, 0), n_free - 1);
            val = free_page[pidx] * PAGE + (pos & (PAGE - 1));
        }
        out[os + t] = val;
    }
}

extern "C" void kernel_launch(void* const* d_in, const int* in_sizes, int n_in,
                              void* d_out, int out_size, void* d_ws, size_t ws_size,
                              hipStream_t stream) {
    const int* pre_lens  = (const int*)d_in[0];
    const int* seq_lens  = (const int*)d_in[1];
    const int* last_loc  = (const int*)d_in[2];
    const int* free_page = (const int*)d_in[3];
    int B      = in_sizes[0];
    int n_free = in_sizes[3];
    int* out   = (int*)d_out;

    int* out_start  = (int*)d_ws;
    int* page_start = out_start + B;

    scan_kernel<<<1, 1024, 0, stream>>>(pre_lens, seq_lens, out_start, page_start, B);
    fill_kernel<<<B, 256, 0, stream>>>(pre_lens, seq_lens, last_loc, free_page,
                                       out_start, page_start, out, n_free);
}

// Round 2
// 18.204 us; speedup vs baseline: 1.2978x; 1.2978x over previous
//
#include <hip/hip_runtime.h>
#include <stdint.h>

#define PAGE 16

// Fused kernel: one block per batch element.
// Each block redundantly computes its exclusive prefix sums (extend tokens,
// new pages) over b' < b -- inputs are 4 KB each, L1/L2 resident broadcast --
// then writes its output segment with int4-vectorized coalesced stores.
__global__ __launch_bounds__(256) void fused_fill(
        const int* __restrict__ pre_lens,
        const int* __restrict__ seq_lens,
        const int* __restrict__ last_loc,
        const int* __restrict__ free_page,
        int* __restrict__ out,
        int B, int n_free) {
    const int b   = blockIdx.x;
    const int tid = threadIdx.x;

    // ---- per-block exclusive prefix over b' < b ----
    int pe = 0, pp = 0;
    for (int i = tid; i < b; i += 256) {
        int pre = pre_lens[i];
        int seq = seq_lens[i];
        pe += seq - pre;
        pp += ((seq + PAGE - 1) >> 4) - ((pre + PAGE - 1) >> 4);
    }
    // wave reduce (64 lanes)
    #pragma unroll
    for (int off = 32; off; off >>= 1) {
        pe += __shfl_down(pe, off);
        pp += __shfl_down(pp, off);
    }
    __shared__ int se[4], sp[4];
    const int wave = tid >> 6, lane = tid & 63;
    if (lane == 0) { se[wave] = pe; sp[wave] = pp; }
    __syncthreads();
    const int os = se[0] + se[1] + se[2] + se[3];   // out_start[b]
    const int ps = sp[0] + sp[1] + sp[2] + sp[3];   // page_start[b]

    // ---- per-sequence parameters ----
    const int pre  = pre_lens[b];
    const int seq  = seq_lens[b];
    const int ext  = seq - pre;
    const int last = last_loc[b];
    const int npb  = (pre + PAGE - 1) >> 4;
    const int boundary = npb * PAGE;     // end of the partial first page
    const int basep    = ps - npb;       // pidx = basep + pos/16

    int* __restrict__ seg = out + os;

    auto val = [&](int t) -> int {
        int pos = pre + t;
        if (pos < boundary) {
            return last + 1 + t;
        }
        int pidx = basep + (pos >> 4);
        pidx = min(max(pidx, 0), n_free - 1);   // defensive (matches ref clip)
        return free_page[pidx] * PAGE + (pos & (PAGE - 1));
    };

    // ---- head peel to 16B alignment ----
    int head = (int)((16u - ((uint32_t)(uintptr_t)seg & 15u)) & 15u) >> 2;
    if (head > ext) head = ext;
    if (tid < head) seg[tid] = val(tid);

    // ---- int4 main body ----
    const int nvec = (ext - head) >> 2;
    for (int v = tid; v < nvec; v += 256) {
        const int t = head + v * 4;
        int4 o;
        o.x = val(t);
        o.y = val(t + 1);
        o.z = val(t + 2);
        o.w = val(t + 3);
        *(int4*)(seg + t) = o;
    }

    // ---- tail ----
    for (int t = head + nvec * 4 + tid; t < ext; t += 256) {
        seg[t] = val(t);
    }
}

extern "C" void kernel_launch(void* const* d_in, const int* in_sizes, int n_in,
                              void* d_out, int out_size, void* d_ws, size_t ws_size,
                              hipStream_t stream) {
    const int* pre_lens  = (const int*)d_in[0];
    const int* seq_lens  = (const int*)d_in[1];
    const int* last_loc  = (const int*)d_in[2];
    const int* free_page = (const int*)d_in[3];
    const int B      = in_sizes[0];
    const int n_free = in_sizes[3];
    int* out = (int*)d_out;

    fused_fill<<<B, 256, 0, stream>>>(pre_lens, seq_lens, last_loc, free_page,
                                      out, B, n_free);
}

// Round 4
// 14.852 us; speedup vs baseline: 1.5907x; 1.2257x over previous
//
#include <hip/hip_runtime.h>
#include <stdint.h>

#define PAGE 16

typedef int v4i __attribute__((ext_vector_type(4)));

// Fused kernel: one block (512 threads = 8 waves) per batch element.
// grid 1024 x 8 waves = 8192 waves = exactly full chip occupancy.
// Each block redundantly computes its exclusive prefix sums (extend tokens,
// new pages) over b' < b -- inputs are 4 KB each, L1/L2 resident broadcast --
// then writes its output segment with nontemporal int4 coalesced stores.
__global__ __launch_bounds__(512) void fused_fill(
        const int* __restrict__ pre_lens,
        const int* __restrict__ seq_lens,
        const int* __restrict__ last_loc,
        const int* __restrict__ free_page,
        int* __restrict__ out,
        int B, int n_free) {
    const int b   = blockIdx.x;
    const int tid = threadIdx.x;

    // ---- per-block exclusive prefix over b' < b ----
    int pe = 0, pp = 0;
    for (int i = tid; i < b; i += 512) {
        int pre = pre_lens[i];
        int seq = seq_lens[i];
        pe += seq - pre;
        pp += ((seq + PAGE - 1) >> 4) - ((pre + PAGE - 1) >> 4);
    }
    // wave reduce (64 lanes)
    #pragma unroll
    for (int off = 32; off; off >>= 1) {
        pe += __shfl_down(pe, off);
        pp += __shfl_down(pp, off);
    }
    __shared__ int se[8], sp[8];
    const int wave = tid >> 6, lane = tid & 63;
    if (lane == 0) { se[wave] = pe; sp[wave] = pp; }
    __syncthreads();
    int os = 0, ps = 0;
    #pragma unroll
    for (int w = 0; w < 8; ++w) { os += se[w]; ps += sp[w]; }

    // ---- per-sequence parameters ----
    const int pre  = pre_lens[b];
    const int seq  = seq_lens[b];
    const int ext  = seq - pre;
    const int last = last_loc[b];
    const int npb  = (pre + PAGE - 1) >> 4;
    const int boundary = npb * PAGE;     // end of the partial first page
    const int basep    = ps - npb;       // pidx = basep + pos/16

    int* __restrict__ seg = out + os;

    auto val = [&](int t) -> int {
        int pos = pre + t;
        if (pos < boundary) {
            return last + 1 + t;
        }
        int pidx = basep + (pos >> 4);
        pidx = min(max(pidx, 0), n_free - 1);   // defensive (matches ref clip)
        return free_page[pidx] * PAGE + (pos & (PAGE - 1));
    };

    // ---- head peel to 16B alignment ----
    int head = (int)((16u - ((uint32_t)(uintptr_t)seg & 15u)) & 15u) >> 2;
    if (head > ext) head = ext;
    if (tid < head) seg[tid] = val(tid);

    // ---- int4 main body (nontemporal streaming stores) ----
    const int nvec = (ext - head) >> 2;
    for (int v = tid; v < nvec; v += 512) {
        const int t = head + v * 4;
        v4i o;
        o.x = val(t);
        o.y = val(t + 1);
        o.z = val(t + 2);
        o.w = val(t + 3);
        __builtin_nontemporal_store(o, (v4i*)(seg + t));
    }

    // ---- tail ----
    for (int t = head + nvec * 4 + tid; t < ext; t += 512) {
        seg[t] = val(t);
    }
}

extern "C" void kernel_launch(void* const* d_in, const int* in_sizes, int n_in,
                              void* d_out, int out_size, void* d_ws, size_t ws_size,
                              hipStream_t stream) {
    const int* pre_lens  = (const int*)d_in[0];
    const int* seq_lens  = (const int*)d_in[1];
    const int* last_loc  = (const int*)d_in[2];
    const int* free_page = (const int*)d_in[3];
    const int B      = in_sizes[0];
    const int n_free = in_sizes[3];
    int* out = (int*)d_out;

    fused_fill<<<B, 512, 0, stream>>>(pre_lens, seq_lens, last_loc, free_page,
                                      out, B, n_free);
}

// Round 5
// 13.857 us; speedup vs baseline: 1.7049x; 1.0718x over previous
//
#include <hip/hip_runtime.h>
#include <stdint.h>

#define PAGE 16

typedef int v4i __attribute__((ext_vector_type(4)));

// Fused kernel: one block (512 threads = 8 waves) per batch element.
// grid 1024 x 8 waves = 8192 waves = full chip occupancy.
// Each block redundantly computes its exclusive prefix sums (extend tokens,
// new pages) over b' < b -- inputs are 4 KB each, L1/L2 resident broadcast --
// then writes its output segment with nontemporal int4 coalesced stores.
__global__ __launch_bounds__(512) void fused_fill(
        const int* __restrict__ pre_lens,
        const int* __restrict__ seq_lens,
        const int* __restrict__ last_loc,
        const int* __restrict__ free_page,
        int* __restrict__ out,
        int B, int n_free) {
    const int b   = blockIdx.x;
    const int tid = threadIdx.x;

    // ---- per-block exclusive prefix over b' < b ----
    int pe = 0, pp = 0;
    for (int i = tid; i < b; i += 512) {
        int pre = pre_lens[i];
        int seq = seq_lens[i];
        pe += seq - pre;
        pp += ((seq + PAGE - 1) >> 4) - ((pre + PAGE - 1) >> 4);
    }
    // wave butterfly reduce (64 lanes)
    #pragma unroll
    for (int off = 32; off; off >>= 1) {
        pe += __shfl_xor(pe, off);
        pp += __shfl_xor(pp, off);
    }
    __shared__ int se[8], sp[8];
    const int wave = tid >> 6, lane = tid & 63;
    if (lane == 0) { se[wave] = pe; sp[wave] = pp; }
    __syncthreads();
    int os = 0, ps = 0;
    #pragma unroll
    for (int w = 0; w < 8; ++w) { os += se[w]; ps += sp[w]; }

    // ---- per-sequence parameters ----
    const int pre  = pre_lens[b];
    const int seq  = seq_lens[b];
    const int ext  = seq - pre;
    const int last = last_loc[b];
    const int npb  = (pre + PAGE - 1) >> 4;
    const int boundary = npb * PAGE;     // end of the partial first page
    const int basep    = ps - npb;       // pidx = basep + pos/16

    int* __restrict__ seg = out + os;

    auto val = [&](int t) -> int {
        int pos = pre + t;
        if (pos < boundary) {
            return last + 1 + t;
        }
        // in-range by construction on this branch (ref's clip only guards
        // lanes it discards): pidx in [page_start, page_start + new_pages)
        return free_page[basep + (pos >> 4)] * PAGE + (pos & (PAGE - 1));
    };

    // ---- head peel to 16B alignment ----
    int head = (int)((16u - ((uint32_t)(uintptr_t)seg & 15u)) & 15u) >> 2;
    if (head > ext) head = ext;
    if (tid < head) seg[tid] = val(tid);

    // ---- int4 main body (nontemporal streaming stores) ----
    const int nvec = (ext - head) >> 2;
    for (int v = tid; v < nvec; v += 512) {
        const int t = head + v * 4;
        const int pos = pre + t;
        v4i o;
        if (pos >= boundary) {
            // fully in the paged region: 4 consecutive tokens span <= 2 pages
            const int p0 = free_page[basep + (pos >> 4)] * PAGE;
            const int m0 = pos & 15;
            if (m0 <= 12) {            // all four tokens in one page
                o.x = p0 + m0;
                o.y = p0 + m0 + 1;
                o.z = p0 + m0 + 2;
                o.w = p0 + m0 + 3;
            } else {                   // straddles a page boundary
                const int p1 = free_page[basep + ((pos + 3) >> 4)] * PAGE;
                o.x = p0 + m0;
                o.y = (m0 + 1 <= 15 ? p0 + ((m0 + 1) & 15) : p1 + ((m0 + 1) & 15));
                o.z = (m0 + 2 <= 15 ? p0 + ((m0 + 2) & 15) : p1 + ((m0 + 2) & 15));
                o.w = p1 + ((m0 + 3) & 15);
            }
        } else {
            o.x = val(t);
            o.y = val(t + 1);
            o.z = val(t + 2);
            o.w = val(t + 3);
        }
        __builtin_nontemporal_store(o, (v4i*)(seg + t));
    }

    // ---- tail ----
    for (int t = head + nvec * 4 + tid; t < ext; t += 512) {
        seg[t] = val(t);
    }
}

extern "C" void kernel_launch(void* const* d_in, const int* in_sizes, int n_in,
                              void* d_out, int out_size, void* d_ws, size_t ws_size,
                              hipStream_t stream) {
    const int* pre_lens  = (const int*)d_in[0];
    const int* seq_lens  = (const int*)d_in[1];
    const int* last_loc  = (const int*)d_in[2];
    const int* free_page = (const int*)d_in[3];
    const int B      = in_sizes[0];
    const int n_free = in_sizes[3];
    int* out = (int*)d_out;

    fused_fill<<<B, 512, 0, stream>>>(pre_lens, seq_lens, last_loc, free_page,
                                      out, B, n_free);
}